// Round 1
// baseline (129.269 us; speedup 1.0000x reference)
//
#include <hip/hip_runtime.h>
#include <math.h>

#define DD 128
#define TAU2 2.0f
#define EPSV 1e-12f

// ---------------------------------------------------------------------------
// Baseline: base_ev[d] = exp(log_be[d]);  base_ar[d] = suffix-sum over d of
// (exp(log_be)+exp(log_bc)). One block of 128 threads, LDS suffix scan.
// ---------------------------------------------------------------------------
__global__ void baseline_kernel(const float* __restrict__ log_be,
                                const float* __restrict__ log_bc,
                                float* __restrict__ base_ev,
                                float* __restrict__ base_ar) {
    __shared__ float sm[DD];
    int d = threadIdx.x;
    float be = expf(log_be[d]);
    float bc = expf(log_bc[d]);
    base_ev[d] = be;
    sm[d] = be + bc;
    __syncthreads();
    #pragma unroll
    for (int off = 1; off < DD; off <<= 1) {
        float v = (d + off < DD) ? sm[d + off] : 0.0f;
        __syncthreads();
        sm[d] += v;
        __syncthreads();
    }
    base_ar[d] = sm[d];
}

// ---------------------------------------------------------------------------
// Prep: per exemplar row e (one 128-thread block):
//   ws_ev[row][d] = exp(log_ev[e][d])
//   ws_ar[row][d] = suffix_sum_{d'>=d} (exp(log_ev[e][d']) + exp(log_cen[e][d']))
// ---------------------------------------------------------------------------
__global__ __launch_bounds__(DD) void prep_kernel(
    const float* __restrict__ log_ev,
    const float* __restrict__ log_cen,
    float* __restrict__ ws_ev,
    float* __restrict__ ws_ar,
    int c0) {
    __shared__ float sm[DD];
    int d = threadIdx.x;
    long long e = (long long)blockIdx.x + c0;
    size_t idx = (size_t)e * DD + d;
    float ev = expf(log_ev[idx]);
    float cn = expf(log_cen[idx]);
    size_t widx = (size_t)blockIdx.x * DD + d;
    ws_ev[widx] = ev;
    sm[d] = ev + cn;
    __syncthreads();
    #pragma unroll
    for (int off = 1; off < DD; off <<= 1) {
        float v = (d + off < DD) ? sm[d + off] : 0.0f;
        __syncthreads();
        sm[d] += v;
        __syncthreads();
    }
    ws_ar[widx] = sm[d];
}

// ---------------------------------------------------------------------------
// Gather: one block (256 threads = 4 waves) per output row b.
// Stage w[k], labels[k] in LDS. Each wave owns 32 of the K=128 neighbors;
// each lane accumulates a float2 column pair (64 lanes * 8B = full 512B row
// per table per k -> perfectly coalesced). Cross-wave reduce via LDS, then
// accumulate into ws accumulators (chunk-safe += ).
// ---------------------------------------------------------------------------
__global__ __launch_bounds__(256) void gather_kernel(
    const float* __restrict__ sq_dists,   // [B,K]
    const int*   __restrict__ labels,     // [B,K]
    const float* __restrict__ ws_ev,      // [chunk,D]
    const float* __restrict__ ws_ar,      // [chunk,D]
    float* __restrict__ acc_num,          // [B,D]
    float* __restrict__ acc_den,          // [B,D]
    int K, int c0, int c1) {
    __shared__ float w_s[128];
    __shared__ int   lab_s[128];
    __shared__ float rn[4][DD];
    __shared__ float rd[4][DD];

    int b = blockIdx.x;
    int tid = threadIdx.x;
    if (tid < K) {
        float sqd = sq_dists[(size_t)b * K + tid];
        w_s[tid]  = (sqd <= TAU2) ? expf(-sqd) : 0.0f;
        lab_s[tid] = labels[(size_t)b * K + tid];
    }
    __syncthreads();

    int wid = tid >> 6;
    int lane = tid & 63;
    int col = lane * 2;

    float nx = 0.f, ny = 0.f, dx = 0.f, dy = 0.f;
    int kpw = (K + 3) >> 2;   // k's per wave
    for (int i = 0; i < kpw; ++i) {
        int k = wid * kpw + i;
        if (k >= K) break;
        int l = lab_s[k];
        if (l >= c0 && l < c1) {
            float wk = w_s[k];
            size_t roff = (size_t)(l - c0) * DD + col;
            float2 e2 = *(const float2*)(ws_ev + roff);
            float2 a2 = *(const float2*)(ws_ar + roff);
            nx += wk * e2.x; ny += wk * e2.y;
            dx += wk * a2.x; dy += wk * a2.y;
        }
    }
    rn[wid][col] = nx; rn[wid][col + 1] = ny;
    rd[wid][col] = dx; rd[wid][col + 1] = dy;
    __syncthreads();

    if (tid < DD) {
        float n  = rn[0][tid] + rn[1][tid] + rn[2][tid] + rn[3][tid];
        float dn = rd[0][tid] + rd[1][tid] + rd[2][tid] + rd[3][tid];
        size_t o = (size_t)b * DD + tid;
        acc_num[o] += n;
        acc_den[o] += dn;
    }
}

// ---------------------------------------------------------------------------
// Finalize: out = clip((num + base_ev) / (den + base_ar + eps), eps, 1-eps)
// ---------------------------------------------------------------------------
__global__ void finalize_kernel(const float* __restrict__ acc_num,
                                const float* __restrict__ acc_den,
                                const float* __restrict__ base_ev,
                                const float* __restrict__ base_ar,
                                float* __restrict__ out, int total) {
    int i = blockIdx.x * blockDim.x + threadIdx.x;
    if (i >= total) return;
    int d = i & (DD - 1);
    float n  = acc_num[i] + base_ev[d];
    float dn = acc_den[i] + base_ar[d] + EPSV;
    float r = n / dn;
    r = fminf(fmaxf(r, EPSV), 1.0f - EPSV);
    out[i] = r;
}

extern "C" void kernel_launch(void* const* d_in, const int* in_sizes, int n_in,
                              void* d_out, int out_size, void* d_ws, size_t ws_size,
                              hipStream_t stream) {
    const float* sq_dists = (const float*)d_in[0];
    const float* log_ev   = (const float*)d_in[1];
    const float* log_cen  = (const float*)d_in[2];
    const float* log_be   = (const float*)d_in[3];
    const float* log_bc   = (const float*)d_in[4];
    const int*   labels   = (const int*)d_in[5];
    float* out = (float*)d_out;

    const int Dv = in_sizes[3];            // 128
    const long long E = (long long)in_sizes[1] / Dv;   // 100000
    const int B = out_size / Dv;           // 4096
    const int K = in_sizes[0] / B;         // 128

    float* ws = (float*)d_ws;
    size_t ws_floats = ws_size / sizeof(float);
    float* acc_num  = ws;                              // B*D
    float* acc_den  = acc_num + (size_t)B * Dv;        // B*D
    float* base_ev  = acc_den + (size_t)B * Dv;        // D
    float* base_ar  = base_ev + Dv;                    // D
    float* chunk_buf = base_ar + Dv;                   // 2 * chunk * D

    size_t head = 2 * (size_t)B * Dv + 2 * (size_t)Dv;
    long long chunk = 0;
    if (ws_floats > head)
        chunk = (long long)((ws_floats - head) / (2 * (size_t)Dv));
    if (chunk > E) chunk = E;
    if (chunk < 1) chunk = 1;  // degenerate; assume ws is big enough in practice

    // zero accumulators (num+den contiguous)
    hipMemsetAsync(acc_num, 0, 2 * (size_t)B * Dv * sizeof(float), stream);

    baseline_kernel<<<1, Dv, 0, stream>>>(log_be, log_bc, base_ev, base_ar);

    for (long long c0 = 0; c0 < E; c0 += chunk) {
        long long c1 = c0 + chunk; if (c1 > E) c1 = E;
        long long rows = c1 - c0;
        float* ws_ev = chunk_buf;
        float* ws_ar = chunk_buf + (size_t)rows * Dv;
        prep_kernel<<<(int)rows, Dv, 0, stream>>>(log_ev, log_cen, ws_ev, ws_ar, (int)c0);
        gather_kernel<<<B, 256, 0, stream>>>(sq_dists, labels, ws_ev, ws_ar,
                                             acc_num, acc_den, K, (int)c0, (int)c1);
    }

    finalize_kernel<<<(B * Dv + 255) / 256, 256, 0, stream>>>(
        acc_num, acc_den, base_ev, base_ar, out, B * Dv);
}

// Round 2
// 87.343 us; speedup vs baseline: 1.4800x; 1.4800x over previous
//
#include <hip/hip_runtime.h>
#include <hip/hip_fp16.h>
#include <math.h>

#define DD 128
#define TAU2 2.0f
#define EPSV 1e-12f

// ---------------------------------------------------------------------------
// Baseline: base_ev[d] = exp(log_be[d]);  base_ar[d] = suffix-sum of
// (exp(log_be)+exp(log_bc)). One block of 128 threads, LDS suffix scan.
// ---------------------------------------------------------------------------
__global__ void baseline_kernel(const float* __restrict__ log_be,
                                const float* __restrict__ log_bc,
                                float* __restrict__ base_ev,
                                float* __restrict__ base_ar) {
    __shared__ float sm[DD];
    int d = threadIdx.x;
    float be = expf(log_be[d]);
    float bc = expf(log_bc[d]);
    base_ev[d] = be;
    sm[d] = be + bc;
    __syncthreads();
    #pragma unroll
    for (int off = 1; off < DD; off <<= 1) {
        float v = (d + off < DD) ? sm[d + off] : 0.0f;
        __syncthreads();
        sm[d] += v;
        __syncthreads();
    }
    base_ar[d] = sm[d];
}

// ---------------------------------------------------------------------------
// Prep: 256-thread blocks, 2 exemplar rows per block. Per row e:
//   ev[d] = exp(log_ev[e][d]);  ar[d] = suffix_sum_{d'>=d}(ev + exp(log_cen))
// Output packed fp16, interleaved per column pair:
//   tab[row][l] (l in 0..63) = {ev[2l], ev[2l+1], ar[2l], ar[2l+1]}  (8 bytes)
// Row stride = 256 ushorts = 512 B.
// ---------------------------------------------------------------------------
__global__ __launch_bounds__(256) void prep_kernel(
    const float* __restrict__ log_ev,
    const float* __restrict__ log_cen,
    unsigned short* __restrict__ tab,
    int c0, long long E) {
    __shared__ float ev_s[2][DD];
    __shared__ float sm[2][DD];
    int tid = threadIdx.x;
    int r = tid >> 7;          // row within block (0..1)
    int d = tid & (DD - 1);
    long long row = (long long)blockIdx.x * 2 + r;   // row within chunk
    long long e = row + c0;                          // global exemplar
    bool valid = (e < E);
    float ev = 0.f, cn = 0.f;
    if (valid) {
        size_t idx = (size_t)e * DD + d;
        ev = expf(log_ev[idx]);
        cn = expf(log_cen[idx]);
    }
    ev_s[r][d] = ev;
    sm[r][d] = ev + cn;
    __syncthreads();
    #pragma unroll
    for (int off = 1; off < DD; off <<= 1) {
        float v = (d + off < DD) ? sm[r][d + off] : 0.0f;
        __syncthreads();
        sm[r][d] += v;
        __syncthreads();
    }
    // threads 0..127 write packets: rr = tid>>6, l = tid&63
    if (tid < 128) {
        int rr = tid >> 6;
        int l = tid & 63;
        long long wrow = (long long)blockIdx.x * 2 + rr;
        if (wrow + c0 < E) {
            __half2 e2 = __floats2half2_rn(ev_s[rr][2 * l], ev_s[rr][2 * l + 1]);
            __half2 a2 = __floats2half2_rn(sm[rr][2 * l], sm[rr][2 * l + 1]);
            uint2 pkt;
            pkt.x = *(unsigned int*)&e2;
            pkt.y = *(unsigned int*)&a2;
            *(uint2*)(tab + (size_t)wrow * 256 + (size_t)l * 4) = pkt;
        }
    }
}

// ---------------------------------------------------------------------------
// Gather: one block (256 threads = 4 waves) per output row b.
// Stage w[k], labels[k] in LDS. Each wave owns 32 neighbors; each lane reads
// ONE 8B packet per neighbor (64 lanes x 8B = full 512B combined ev+ar row,
// perfectly coalesced). Cross-wave LDS reduce, then fused finalize
// (baseline add + divide + clip) written directly to out.
// ---------------------------------------------------------------------------
__global__ __launch_bounds__(256) void gather_kernel(
    const float* __restrict__ sq_dists,        // [B,K]
    const int*   __restrict__ labels,          // [B,K]
    const unsigned short* __restrict__ tab,    // [chunk][256] packed fp16
    const float* __restrict__ base_ev,         // [D]
    const float* __restrict__ base_ar,         // [D]
    float* __restrict__ acc_num,               // [B,D] (chunked path)
    float* __restrict__ acc_den,               // [B,D]
    float* __restrict__ out,                   // [B,D] (fused path)
    int K, int c0, int c1, int fused) {
    __shared__ float w_s[256];
    __shared__ int   lab_s[256];
    __shared__ float rn[4][DD];
    __shared__ float rd[4][DD];

    int b = blockIdx.x;
    int tid = threadIdx.x;
    if (tid < K) {
        float sqd = sq_dists[(size_t)b * K + tid];
        w_s[tid]  = (sqd <= TAU2) ? expf(-sqd) : 0.0f;
        lab_s[tid] = labels[(size_t)b * K + tid];
    }
    __syncthreads();

    int wid = tid >> 6;
    int lane = tid & 63;
    const unsigned short* lbase = tab + (size_t)lane * 4;

    float nx = 0.f, ny = 0.f, dx = 0.f, dy = 0.f;
    if (fused && K == 128) {
        int k0 = wid << 5;
        #pragma unroll 8
        for (int i = 0; i < 32; ++i) {
            int k = k0 + i;
            int l = lab_s[k];
            float wk = w_s[k];
            uint2 pkt = *(const uint2*)(lbase + (size_t)l * 256);
            float2 ef = __half22float2(*(const __half2*)&pkt.x);
            float2 af = __half22float2(*(const __half2*)&pkt.y);
            nx = fmaf(wk, ef.x, nx); ny = fmaf(wk, ef.y, ny);
            dx = fmaf(wk, af.x, dx); dy = fmaf(wk, af.y, dy);
        }
    } else {
        int kpw = (K + 3) >> 2;
        for (int i = 0; i < kpw; ++i) {
            int k = wid * kpw + i;
            if (k >= K) break;
            int l = lab_s[k];
            if (l >= c0 && l < c1) {
                float wk = w_s[k];
                uint2 pkt = *(const uint2*)(lbase + (size_t)(l - c0) * 256);
                float2 ef = __half22float2(*(const __half2*)&pkt.x);
                float2 af = __half22float2(*(const __half2*)&pkt.y);
                nx = fmaf(wk, ef.x, nx); ny = fmaf(wk, ef.y, ny);
                dx = fmaf(wk, af.x, dx); dy = fmaf(wk, af.y, dy);
            }
        }
    }
    int col = lane * 2;
    rn[wid][col] = nx; rn[wid][col + 1] = ny;
    rd[wid][col] = dx; rd[wid][col + 1] = dy;
    __syncthreads();

    if (tid < DD) {
        float n  = rn[0][tid] + rn[1][tid] + rn[2][tid] + rn[3][tid];
        float dn = rd[0][tid] + rd[1][tid] + rd[2][tid] + rd[3][tid];
        size_t o = (size_t)b * DD + tid;
        if (fused) {
            n  += base_ev[tid];
            dn += base_ar[tid] + EPSV;
            float r = n / dn;
            out[o] = fminf(fmaxf(r, EPSV), 1.0f - EPSV);
        } else {
            acc_num[o] += n;
            acc_den[o] += dn;
        }
    }
}

// ---------------------------------------------------------------------------
// Finalize (chunked fallback only)
// ---------------------------------------------------------------------------
__global__ void finalize_kernel(const float* __restrict__ acc_num,
                                const float* __restrict__ acc_den,
                                const float* __restrict__ base_ev,
                                const float* __restrict__ base_ar,
                                float* __restrict__ out, int total) {
    int i = blockIdx.x * blockDim.x + threadIdx.x;
    if (i >= total) return;
    int d = i & (DD - 1);
    float n  = acc_num[i] + base_ev[d];
    float dn = acc_den[i] + base_ar[d] + EPSV;
    float r = n / dn;
    r = fminf(fmaxf(r, EPSV), 1.0f - EPSV);
    out[i] = r;
}

extern "C" void kernel_launch(void* const* d_in, const int* in_sizes, int n_in,
                              void* d_out, int out_size, void* d_ws, size_t ws_size,
                              hipStream_t stream) {
    const float* sq_dists = (const float*)d_in[0];
    const float* log_ev   = (const float*)d_in[1];
    const float* log_cen  = (const float*)d_in[2];
    const float* log_be   = (const float*)d_in[3];
    const float* log_bc   = (const float*)d_in[4];
    const int*   labels   = (const int*)d_in[5];
    float* out = (float*)d_out;

    const int Dv = in_sizes[3];                        // 128
    const long long E = (long long)in_sizes[1] / Dv;   // 100000
    const int B = out_size / Dv;                       // 4096
    const int K = in_sizes[0] / B;                     // 128

    // ws layout: [acc_num B*D][acc_den B*D][base_ev D][base_ar D][table ...]
    float* ws = (float*)d_ws;
    float* acc_num = ws;
    float* acc_den = acc_num + (size_t)B * Dv;
    float* base_ev = acc_den + (size_t)B * Dv;
    float* base_ar = base_ev + Dv;
    size_t head_floats = 2 * (size_t)B * Dv + 2 * (size_t)Dv;
    unsigned short* tab = (unsigned short*)(ws + head_floats);

    size_t head_bytes = head_floats * sizeof(float);
    long long cap = 0;
    if (ws_size > head_bytes)
        cap = (long long)((ws_size - head_bytes) / (2 * (size_t)Dv * sizeof(unsigned short)));
    long long chunk = cap > E ? E : cap;
    if (chunk < 1) chunk = 1;

    baseline_kernel<<<1, Dv, 0, stream>>>(log_be, log_bc, base_ev, base_ar);

    if (chunk >= E) {
        // single-chunk fused path
        int pblocks = (int)((E + 1) / 2);
        prep_kernel<<<pblocks, 256, 0, stream>>>(log_ev, log_cen, tab, 0, E);
        gather_kernel<<<B, 256, 0, stream>>>(sq_dists, labels, tab,
                                             base_ev, base_ar,
                                             acc_num, acc_den, out,
                                             K, 0, (int)E, 1);
    } else {
        hipMemsetAsync(acc_num, 0, 2 * (size_t)B * Dv * sizeof(float), stream);
        for (long long c0 = 0; c0 < E; c0 += chunk) {
            long long c1 = c0 + chunk; if (c1 > E) c1 = E;
            long long rows = c1 - c0;
            int pblocks = (int)((rows + 1) / 2);
            prep_kernel<<<pblocks, 256, 0, stream>>>(log_ev, log_cen, tab, (int)c0, E);
            gather_kernel<<<B, 256, 0, stream>>>(sq_dists, labels, tab,
                                                 base_ev, base_ar,
                                                 acc_num, acc_den, out,
                                                 K, (int)c0, (int)c1, 0);
        }
        finalize_kernel<<<(B * Dv + 255) / 256, 256, 0, stream>>>(
            acc_num, acc_den, base_ev, base_ar, out, B * Dv);
    }
}

// Round 3
// 70.347 us; speedup vs baseline: 1.8376x; 1.2416x over previous
//
#include <hip/hip_runtime.h>
#include <hip/hip_fp16.h>
#include <math.h>

#define DD 128
#define TAU2 2.0f
#define EPSV 1e-12f

// ---------------------------------------------------------------------------
// Baseline: base_ev[d] = exp(log_be[d]);  base_ar[d] = suffix-sum of
// (exp(log_be)+exp(log_bc)). One block of 128 threads, LDS suffix scan.
// ---------------------------------------------------------------------------
__global__ void baseline_kernel(const float* __restrict__ log_be,
                                const float* __restrict__ log_bc,
                                float* __restrict__ base_ev,
                                float* __restrict__ base_ar) {
    __shared__ float sm[DD];
    int d = threadIdx.x;
    float be = expf(log_be[d]);
    float bc = expf(log_bc[d]);
    base_ev[d] = be;
    sm[d] = be + bc;
    __syncthreads();
    #pragma unroll
    for (int off = 1; off < DD; off <<= 1) {
        float v = (d + off < DD) ? sm[d + off] : 0.0f;
        __syncthreads();
        sm[d] += v;
        __syncthreads();
    }
    base_ar[d] = sm[d];
}

// ---------------------------------------------------------------------------
// Prep (wave-per-row, shuffle suffix scan, zero barriers):
// lane l owns columns 2l, 2l+1 of its row. Load float2 from each log table,
// exp via __expf, 6-step __shfl_down suffix scan of pair-totals across the
// wave, then pack {ev0,ev1,ar0,ar1} as 2x half2 into one 8B packet:
//   tab[row][l] = {ev[2l], ev[2l+1], ar[2l], ar[2l+1]}   (row stride 512 B)
// ---------------------------------------------------------------------------
__global__ __launch_bounds__(256) void prep_kernel(
    const float* __restrict__ log_ev,
    const float* __restrict__ log_cen,
    unsigned short* __restrict__ tab,
    long long c0, long long rows, long long E) {
    int tid = threadIdx.x;
    int lane = tid & 63;
    long long wave = ((long long)blockIdx.x * blockDim.x + tid) >> 6;
    long long nwaves = ((long long)gridDim.x * blockDim.x) >> 6;

    for (long long row = wave; row < rows; row += nwaves) {
        long long e = row + c0;
        size_t idx = ((size_t)e * DD + 2 * lane);
        float2 le = *(const float2*)(log_ev + idx);
        float2 lc = *(const float2*)(log_cen + idx);
        float ea = __expf(le.x), eb = __expf(le.y);
        float a = ea + __expf(lc.x);
        float b = eb + __expf(lc.y);
        float t = a + b;                 // pair total
        // inclusive suffix scan of t across the wave (lane l gets sum l'>=l)
        #pragma unroll
        for (int off = 1; off < 64; off <<= 1) {
            float v = __shfl_down(t, off, 64);
            t += (lane + off < 64) ? v : 0.0f;
        }
        float ar0 = t;           // suffix starting at col 2l
        float ar1 = t - a;       // suffix starting at col 2l+1
        __half2 e2 = __floats2half2_rn(ea, eb);
        __half2 a2 = __floats2half2_rn(ar0, ar1);
        uint2 pkt;
        pkt.x = *(unsigned int*)&e2;
        pkt.y = *(unsigned int*)&a2;
        *(uint2*)(tab + (size_t)row * 256 + (size_t)lane * 4) = pkt;
    }
}

// ---------------------------------------------------------------------------
// Gather: one block (256 threads = 4 waves) per output row b.
// Stage w[k], labels[k] in LDS. Each wave owns 32 neighbors; each lane reads
// ONE 8B packet per neighbor (64 lanes x 8B = full 512B combined ev+ar row,
// perfectly coalesced). Cross-wave LDS reduce, then fused finalize
// (baseline add + divide + clip) written directly to out.
// ---------------------------------------------------------------------------
__global__ __launch_bounds__(256) void gather_kernel(
    const float* __restrict__ sq_dists,        // [B,K]
    const int*   __restrict__ labels,          // [B,K]
    const unsigned short* __restrict__ tab,    // [chunk][256] packed fp16
    const float* __restrict__ base_ev,         // [D]
    const float* __restrict__ base_ar,         // [D]
    float* __restrict__ acc_num,               // [B,D] (chunked path)
    float* __restrict__ acc_den,               // [B,D]
    float* __restrict__ out,                   // [B,D] (fused path)
    int K, int c0, int c1, int fused) {
    __shared__ float w_s[256];
    __shared__ int   lab_s[256];
    __shared__ float rn[4][DD];
    __shared__ float rd[4][DD];

    int b = blockIdx.x;
    int tid = threadIdx.x;
    if (tid < K) {
        float sqd = sq_dists[(size_t)b * K + tid];
        w_s[tid]  = (sqd <= TAU2) ? __expf(-sqd) : 0.0f;
        lab_s[tid] = labels[(size_t)b * K + tid];
    }
    __syncthreads();

    int wid = tid >> 6;
    int lane = tid & 63;
    const unsigned short* lbase = tab + (size_t)lane * 4;

    float nx = 0.f, ny = 0.f, dx = 0.f, dy = 0.f;
    if (fused && K == 128) {
        int k0 = wid << 5;
        #pragma unroll 8
        for (int i = 0; i < 32; ++i) {
            int k = k0 + i;
            int l = lab_s[k];
            float wk = w_s[k];
            uint2 pkt = *(const uint2*)(lbase + (size_t)l * 256);
            float2 ef = __half22float2(*(const __half2*)&pkt.x);
            float2 af = __half22float2(*(const __half2*)&pkt.y);
            nx = fmaf(wk, ef.x, nx); ny = fmaf(wk, ef.y, ny);
            dx = fmaf(wk, af.x, dx); dy = fmaf(wk, af.y, dy);
        }
    } else {
        int kpw = (K + 3) >> 2;
        for (int i = 0; i < kpw; ++i) {
            int k = wid * kpw + i;
            if (k >= K) break;
            int l = lab_s[k];
            if (l >= c0 && l < c1) {
                float wk = w_s[k];
                uint2 pkt = *(const uint2*)(lbase + (size_t)(l - c0) * 256);
                float2 ef = __half22float2(*(const __half2*)&pkt.x);
                float2 af = __half22float2(*(const __half2*)&pkt.y);
                nx = fmaf(wk, ef.x, nx); ny = fmaf(wk, ef.y, ny);
                dx = fmaf(wk, af.x, dx); dy = fmaf(wk, af.y, dy);
            }
        }
    }
    int col = lane * 2;
    rn[wid][col] = nx; rn[wid][col + 1] = ny;
    rd[wid][col] = dx; rd[wid][col + 1] = dy;
    __syncthreads();

    if (tid < DD) {
        float n  = rn[0][tid] + rn[1][tid] + rn[2][tid] + rn[3][tid];
        float dn = rd[0][tid] + rd[1][tid] + rd[2][tid] + rd[3][tid];
        size_t o = (size_t)b * DD + tid;
        if (fused) {
            n  += base_ev[tid];
            dn += base_ar[tid] + EPSV;
            float r = n / dn;
            out[o] = fminf(fmaxf(r, EPSV), 1.0f - EPSV);
        } else {
            acc_num[o] += n;
            acc_den[o] += dn;
        }
    }
}

// ---------------------------------------------------------------------------
// Finalize (chunked fallback only)
// ---------------------------------------------------------------------------
__global__ void finalize_kernel(const float* __restrict__ acc_num,
                                const float* __restrict__ acc_den,
                                const float* __restrict__ base_ev,
                                const float* __restrict__ base_ar,
                                float* __restrict__ out, int total) {
    int i = blockIdx.x * blockDim.x + threadIdx.x;
    if (i >= total) return;
    int d = i & (DD - 1);
    float n  = acc_num[i] + base_ev[d];
    float dn = acc_den[i] + base_ar[d] + EPSV;
    float r = n / dn;
    r = fminf(fmaxf(r, EPSV), 1.0f - EPSV);
    out[i] = r;
}

extern "C" void kernel_launch(void* const* d_in, const int* in_sizes, int n_in,
                              void* d_out, int out_size, void* d_ws, size_t ws_size,
                              hipStream_t stream) {
    const float* sq_dists = (const float*)d_in[0];
    const float* log_ev   = (const float*)d_in[1];
    const float* log_cen  = (const float*)d_in[2];
    const float* log_be   = (const float*)d_in[3];
    const float* log_bc   = (const float*)d_in[4];
    const int*   labels   = (const int*)d_in[5];
    float* out = (float*)d_out;

    const int Dv = in_sizes[3];                        // 128
    const long long E = (long long)in_sizes[1] / Dv;   // 100000
    const int B = out_size / Dv;                       // 4096
    const int K = in_sizes[0] / B;                     // 128

    // ws layout: [acc_num B*D][acc_den B*D][base_ev D][base_ar D][table ...]
    float* ws = (float*)d_ws;
    float* acc_num = ws;
    float* acc_den = acc_num + (size_t)B * Dv;
    float* base_ev = acc_den + (size_t)B * Dv;
    float* base_ar = base_ev + Dv;
    size_t head_floats = 2 * (size_t)B * Dv + 2 * (size_t)Dv;
    unsigned short* tab = (unsigned short*)(ws + head_floats);

    size_t head_bytes = head_floats * sizeof(float);
    long long cap = 0;
    if (ws_size > head_bytes)
        cap = (long long)((ws_size - head_bytes) / (2 * (size_t)Dv * sizeof(unsigned short)));
    long long chunk = cap > E ? E : cap;
    if (chunk < 1) chunk = 1;

    baseline_kernel<<<1, Dv, 0, stream>>>(log_be, log_bc, base_ev, base_ar);

    if (chunk >= E) {
        // single-chunk fused path
        prep_kernel<<<2048, 256, 0, stream>>>(log_ev, log_cen, tab, 0, E, E);
        gather_kernel<<<B, 256, 0, stream>>>(sq_dists, labels, tab,
                                             base_ev, base_ar,
                                             acc_num, acc_den, out,
                                             K, 0, (int)E, 1);
    } else {
        hipMemsetAsync(acc_num, 0, 2 * (size_t)B * Dv * sizeof(float), stream);
        for (long long c0 = 0; c0 < E; c0 += chunk) {
            long long c1 = c0 + chunk; if (c1 > E) c1 = E;
            long long rows = c1 - c0;
            prep_kernel<<<2048, 256, 0, stream>>>(log_ev, log_cen, tab, c0, rows, E);
            gather_kernel<<<B, 256, 0, stream>>>(sq_dists, labels, tab,
                                                 base_ev, base_ar,
                                                 acc_num, acc_den, out,
                                                 K, (int)c0, (int)c1, 0);
        }
        finalize_kernel<<<(B * Dv + 255) / 256, 256, 0, stream>>>(
            acc_num, acc_den, base_ev, base_ar, out, B * Dv);
    }
}

// Round 4
// 65.470 us; speedup vs baseline: 1.9745x; 1.0745x over previous
//
#include <hip/hip_runtime.h>
#include <hip/hip_fp16.h>
#include <math.h>

#define DD 128
#define TAU2 2.0f
#define EPSV 1e-12f

// Packet layout (16 B): packet j (j=0..31) of a row covers cols 4j..4j+3:
//   { half2(ev0,ev1), half2(ev2,ev3), half2(ar0,ar1), half2(ar2,ar3) }
// Row stride = 256 ushorts = 512 B.

// ---------------------------------------------------------------------------
// Prep: half-wave per row. Lane j (j = lane&31) owns cols 4j..4j+3 of row
// (halfwave id). float4 loads (16 B/lane/table), 5-step shuffle suffix scan
// of per-lane 4-col totals, pack + store one uint4 packet per lane.
// Block 0 additionally computes the baseline row (lanes 0..31 of wave 0).
// ---------------------------------------------------------------------------
__global__ __launch_bounds__(256) void prep_kernel(
    const float* __restrict__ log_ev,
    const float* __restrict__ log_cen,
    const float* __restrict__ log_be,
    const float* __restrict__ log_bc,
    unsigned short* __restrict__ tab,
    float* __restrict__ base_ev,
    float* __restrict__ base_ar,
    long long c0, long long rows, int do_base) {
    int tid = threadIdx.x;
    int lane = tid & 63;
    int j = lane & 31;           // packet index within row
    int h = lane >> 5;           // half of wave

    // --- baseline (once, block 0, wave 0, lanes 0..31) ---
    if (do_base && blockIdx.x == 0 && tid < 32) {
        float4 lb = *(const float4*)(log_be + 4 * j);
        float4 lc = *(const float4*)(log_bc + 4 * j);
        float e0 = __expf(lb.x), e1 = __expf(lb.y), e2 = __expf(lb.z), e3 = __expf(lb.w);
        float s0 = e0 + __expf(lc.x), s1 = e1 + __expf(lc.y);
        float s2 = e2 + __expf(lc.z), s3 = e3 + __expf(lc.w);
        float t = s0 + s1 + s2 + s3;
        #pragma unroll
        for (int off = 1; off < 32; off <<= 1) {
            float v = __shfl_down(t, off, 64);
            t += (j + off < 32) ? v : 0.0f;
        }
        *(float4*)(base_ev + 4 * j) = make_float4(e0, e1, e2, e3);
        *(float4*)(base_ar + 4 * j) = make_float4(t, t - s0, t - s0 - s1, t - s0 - s1 - s2);
    }

    long long g = (((long long)blockIdx.x * blockDim.x + tid) >> 6) * 2 + h; // halfwave id
    long long ng = (((long long)gridDim.x * blockDim.x) >> 6) * 2;

    for (long long row = g; row < rows; row += ng) {
        long long e = row + c0;
        size_t idx = (size_t)e * DD + 4 * j;
        float4 le = *(const float4*)(log_ev + idx);
        float4 lc = *(const float4*)(log_cen + idx);
        float e0 = __expf(le.x), e1 = __expf(le.y), e2 = __expf(le.z), e3 = __expf(le.w);
        float s0 = e0 + __expf(lc.x), s1 = e1 + __expf(lc.y);
        float s2 = e2 + __expf(lc.z), s3 = e3 + __expf(lc.w);
        float t = s0 + s1 + s2 + s3;
        // inclusive suffix scan across the 32-lane half (guard keeps halves apart)
        #pragma unroll
        for (int off = 1; off < 32; off <<= 1) {
            float v = __shfl_down(t, off, 64);
            t += (j + off < 32) ? v : 0.0f;
        }
        __half2 ep0 = __floats2half2_rn(e0, e1);
        __half2 ep1 = __floats2half2_rn(e2, e3);
        __half2 ap0 = __floats2half2_rn(t, t - s0);
        __half2 ap1 = __floats2half2_rn(t - s0 - s1, t - s0 - s1 - s2);
        uint4 pkt;
        pkt.x = *(unsigned int*)&ep0;
        pkt.y = *(unsigned int*)&ep1;
        pkt.z = *(unsigned int*)&ap0;
        pkt.w = *(unsigned int*)&ap1;
        *(uint4*)(tab + (size_t)row * 256 + (size_t)j * 8) = pkt;
    }
}

// ---------------------------------------------------------------------------
// Gather: one block (256 threads = 4 waves) per output row b.
// 16 B packets: half-wave reads a full 512 B row (32 lanes x 16 B), so each
// wave processes 2 k's per iteration (h = lane>>5 picks even/odd k).
// Each lane accumulates 4 columns (4j..4j+3). 8 partials (4 waves x 2
// halves) reduced via LDS; fused finalize writes out directly.
// ---------------------------------------------------------------------------
__global__ __launch_bounds__(256) void gather_kernel(
    const float* __restrict__ sq_dists,        // [B,K]
    const int*   __restrict__ labels,          // [B,K]
    const unsigned short* __restrict__ tab,    // [chunk][256] packed fp16
    const float* __restrict__ base_ev,         // [D]
    const float* __restrict__ base_ar,         // [D]
    float* __restrict__ acc_num,               // [B,D] (chunked path)
    float* __restrict__ acc_den,               // [B,D]
    float* __restrict__ out,                   // [B,D] (fused path)
    int K, int c0, int c1, int fused) {
    __shared__ float w_s[128];
    __shared__ int   lab_s[128];
    __shared__ float rn[8][DD];
    __shared__ float rd[8][DD];

    int b = blockIdx.x;
    int tid = threadIdx.x;
    if (tid < K) {
        float sqd = sq_dists[(size_t)b * K + tid];
        w_s[tid]  = (sqd <= TAU2) ? __expf(-sqd) : 0.0f;
        lab_s[tid] = labels[(size_t)b * K + tid];
    }
    __syncthreads();

    int wid = tid >> 6;
    int lane = tid & 63;
    int j = lane & 31;
    int h = lane >> 5;
    const unsigned short* jbase = tab + (size_t)j * 8;

    float n0 = 0.f, n1 = 0.f, n2 = 0.f, n3 = 0.f;
    float d0 = 0.f, d1 = 0.f, d2 = 0.f, d3 = 0.f;

    if (fused && K == 128) {
        int k0 = wid << 5;
        #pragma unroll
        for (int i = 0; i < 16; ++i) {
            int k = k0 + 2 * i + h;
            int l = lab_s[k];
            float wk = w_s[k];
            uint4 pkt = *(const uint4*)(jbase + (size_t)l * 256);
            float2 e01 = __half22float2(*(const __half2*)&pkt.x);
            float2 e23 = __half22float2(*(const __half2*)&pkt.y);
            float2 a01 = __half22float2(*(const __half2*)&pkt.z);
            float2 a23 = __half22float2(*(const __half2*)&pkt.w);
            n0 = fmaf(wk, e01.x, n0); n1 = fmaf(wk, e01.y, n1);
            n2 = fmaf(wk, e23.x, n2); n3 = fmaf(wk, e23.y, n3);
            d0 = fmaf(wk, a01.x, d0); d1 = fmaf(wk, a01.y, d1);
            d2 = fmaf(wk, a23.x, d2); d3 = fmaf(wk, a23.y, d3);
        }
    } else {
        int kpw = (K + 3) >> 2;
        for (int kk = h; kk < kpw; kk += 2) {
            int k = wid * kpw + kk;
            if (k >= K) break;
            int l = lab_s[k];
            if (l >= c0 && l < c1) {
                float wk = w_s[k];
                uint4 pkt = *(const uint4*)(jbase + (size_t)(l - c0) * 256);
                float2 e01 = __half22float2(*(const __half2*)&pkt.x);
                float2 e23 = __half22float2(*(const __half2*)&pkt.y);
                float2 a01 = __half22float2(*(const __half2*)&pkt.z);
                float2 a23 = __half22float2(*(const __half2*)&pkt.w);
                n0 = fmaf(wk, e01.x, n0); n1 = fmaf(wk, e01.y, n1);
                n2 = fmaf(wk, e23.x, n2); n3 = fmaf(wk, e23.y, n3);
                d0 = fmaf(wk, a01.x, d0); d1 = fmaf(wk, a01.y, d1);
                d2 = fmaf(wk, a23.x, d2); d3 = fmaf(wk, a23.y, d3);
            }
        }
    }
    int part = wid * 2 + h;
    *(float4*)&rn[part][4 * j] = make_float4(n0, n1, n2, n3);
    *(float4*)&rd[part][4 * j] = make_float4(d0, d1, d2, d3);
    __syncthreads();

    if (tid < DD) {
        float n  = rn[0][tid] + rn[1][tid] + rn[2][tid] + rn[3][tid]
                 + rn[4][tid] + rn[5][tid] + rn[6][tid] + rn[7][tid];
        float dn = rd[0][tid] + rd[1][tid] + rd[2][tid] + rd[3][tid]
                 + rd[4][tid] + rd[5][tid] + rd[6][tid] + rd[7][tid];
        size_t o = (size_t)b * DD + tid;
        if (fused) {
            n  += base_ev[tid];
            dn += base_ar[tid] + EPSV;
            float r = n / dn;
            out[o] = fminf(fmaxf(r, EPSV), 1.0f - EPSV);
        } else {
            acc_num[o] += n;
            acc_den[o] += dn;
        }
    }
}

// ---------------------------------------------------------------------------
// Finalize (chunked fallback only)
// ---------------------------------------------------------------------------
__global__ void finalize_kernel(const float* __restrict__ acc_num,
                                const float* __restrict__ acc_den,
                                const float* __restrict__ base_ev,
                                const float* __restrict__ base_ar,
                                float* __restrict__ out, int total) {
    int i = blockIdx.x * blockDim.x + threadIdx.x;
    if (i >= total) return;
    int d = i & (DD - 1);
    float n  = acc_num[i] + base_ev[d];
    float dn = acc_den[i] + base_ar[d] + EPSV;
    float r = n / dn;
    r = fminf(fmaxf(r, EPSV), 1.0f - EPSV);
    out[i] = r;
}

extern "C" void kernel_launch(void* const* d_in, const int* in_sizes, int n_in,
                              void* d_out, int out_size, void* d_ws, size_t ws_size,
                              hipStream_t stream) {
    const float* sq_dists = (const float*)d_in[0];
    const float* log_ev   = (const float*)d_in[1];
    const float* log_cen  = (const float*)d_in[2];
    const float* log_be   = (const float*)d_in[3];
    const float* log_bc   = (const float*)d_in[4];
    const int*   labels   = (const int*)d_in[5];
    float* out = (float*)d_out;

    const int Dv = in_sizes[3];                        // 128
    const long long E = (long long)in_sizes[1] / Dv;   // 100000
    const int B = out_size / Dv;                       // 4096
    const int K = in_sizes[0] / B;                     // 128

    // ws layout: [acc_num B*D][acc_den B*D][base_ev D][base_ar D][table ...]
    float* ws = (float*)d_ws;
    float* acc_num = ws;
    float* acc_den = acc_num + (size_t)B * Dv;
    float* base_ev = acc_den + (size_t)B * Dv;
    float* base_ar = base_ev + Dv;
    size_t head_floats = 2 * (size_t)B * Dv + 2 * (size_t)Dv;
    unsigned short* tab = (unsigned short*)(ws + head_floats);

    size_t head_bytes = head_floats * sizeof(float);
    long long cap = 0;
    if (ws_size > head_bytes)
        cap = (long long)((ws_size - head_bytes) / (2 * (size_t)Dv * sizeof(unsigned short)));
    long long chunk = cap > E ? E : cap;
    if (chunk < 1) chunk = 1;

    if (chunk >= E) {
        // single-chunk fused path
        prep_kernel<<<4096, 256, 0, stream>>>(log_ev, log_cen, log_be, log_bc,
                                              tab, base_ev, base_ar, 0, E, 1);
        gather_kernel<<<B, 256, 0, stream>>>(sq_dists, labels, tab,
                                             base_ev, base_ar,
                                             acc_num, acc_den, out,
                                             K, 0, (int)E, 1);
    } else {
        hipMemsetAsync(acc_num, 0, 2 * (size_t)B * Dv * sizeof(float), stream);
        for (long long c0 = 0; c0 < E; c0 += chunk) {
            long long c1 = c0 + chunk; if (c1 > E) c1 = E;
            long long rows = c1 - c0;
            prep_kernel<<<4096, 256, 0, stream>>>(log_ev, log_cen, log_be, log_bc,
                                                  tab, base_ev, base_ar,
                                                  c0, rows, c0 == 0 ? 1 : 0);
            gather_kernel<<<B, 256, 0, stream>>>(sq_dists, labels, tab,
                                                 base_ev, base_ar,
                                                 acc_num, acc_den, out,
                                                 K, (int)c0, (int)c1, 0);
        }
        finalize_kernel<<<(B * Dv + 255) / 256, 256, 0, stream>>>(
            acc_num, acc_den, base_ev, base_ar, out, B * Dv);
    }
}

// Round 5
// 65.400 us; speedup vs baseline: 1.9766x; 1.0011x over previous
//
#include <hip/hip_runtime.h>
#include <hip/hip_fp16.h>
#include <math.h>

#define DD 128
#define TAU2 2.0f
#define EPSV 1e-12f

// Packet layout (16 B): packet j (j=0..31) of a row covers cols 4j..4j+3:
//   { half2(ev0,ev1), half2(ev2,ev3), half2(ar0,ar1), half2(ar2,ar3) }
// Row stride = 256 ushorts = 512 B.

// ---------------------------------------------------------------------------
// Prep: half-wave per row. Lane j (j = lane&31) owns cols 4j..4j+3 of row
// (halfwave id). float4 loads, 5-step shuffle suffix scan, one uint4 packet
// store per lane. Block 0 wave 0 also computes the baseline row.
// ---------------------------------------------------------------------------
__global__ __launch_bounds__(256) void prep_kernel(
    const float* __restrict__ log_ev,
    const float* __restrict__ log_cen,
    const float* __restrict__ log_be,
    const float* __restrict__ log_bc,
    unsigned short* __restrict__ tab,
    float* __restrict__ base_ev,
    float* __restrict__ base_ar,
    long long c0, long long rows, int do_base) {
    int tid = threadIdx.x;
    int lane = tid & 63;
    int j = lane & 31;           // packet index within row
    int h = lane >> 5;           // half of wave

    if (do_base && blockIdx.x == 0 && tid < 32) {
        float4 lb = *(const float4*)(log_be + 4 * j);
        float4 lc = *(const float4*)(log_bc + 4 * j);
        float e0 = __expf(lb.x), e1 = __expf(lb.y), e2 = __expf(lb.z), e3 = __expf(lb.w);
        float s0 = e0 + __expf(lc.x), s1 = e1 + __expf(lc.y);
        float s2 = e2 + __expf(lc.z), s3 = e3 + __expf(lc.w);
        float t = s0 + s1 + s2 + s3;
        #pragma unroll
        for (int off = 1; off < 32; off <<= 1) {
            float v = __shfl_down(t, off, 64);
            t += (j + off < 32) ? v : 0.0f;
        }
        *(float4*)(base_ev + 4 * j) = make_float4(e0, e1, e2, e3);
        *(float4*)(base_ar + 4 * j) = make_float4(t, t - s0, t - s0 - s1, t - s0 - s1 - s2);
    }

    long long g = (((long long)blockIdx.x * blockDim.x + tid) >> 6) * 2 + h;
    long long ng = (((long long)gridDim.x * blockDim.x) >> 6) * 2;

    for (long long row = g; row < rows; row += ng) {
        long long e = row + c0;
        size_t idx = (size_t)e * DD + 4 * j;
        float4 le = *(const float4*)(log_ev + idx);
        float4 lc = *(const float4*)(log_cen + idx);
        float e0 = __expf(le.x), e1 = __expf(le.y), e2 = __expf(le.z), e3 = __expf(le.w);
        float s0 = e0 + __expf(lc.x), s1 = e1 + __expf(lc.y);
        float s2 = e2 + __expf(lc.z), s3 = e3 + __expf(lc.w);
        float t = s0 + s1 + s2 + s3;
        #pragma unroll
        for (int off = 1; off < 32; off <<= 1) {
            float v = __shfl_down(t, off, 64);
            t += (j + off < 32) ? v : 0.0f;
        }
        __half2 ep0 = __floats2half2_rn(e0, e1);
        __half2 ep1 = __floats2half2_rn(e2, e3);
        __half2 ap0 = __floats2half2_rn(t, t - s0);
        __half2 ap1 = __floats2half2_rn(t - s0 - s1, t - s0 - s1 - s2);
        uint4 pkt;
        pkt.x = *(unsigned int*)&ep0;
        pkt.y = *(unsigned int*)&ep1;
        pkt.z = *(unsigned int*)&ap0;
        pkt.w = *(unsigned int*)&ap1;
        *(uint4*)(tab + (size_t)row * 256 + (size_t)j * 8) = pkt;
    }
}

// ---------------------------------------------------------------------------
// Gather: one block (256 threads = 4 waves) per output row b.
// Half-wave reads a full 512 B row (32 lanes x 16 B); wave covers 2 k's per
// step. Inner loop: 2 phases of EXPLICIT 8-deep register prefetch
// (8 outstanding uint4 loads per lane) to cover L3/HBM latency.
// ---------------------------------------------------------------------------
__global__ __launch_bounds__(256) void gather_kernel(
    const float* __restrict__ sq_dists,        // [B,K]
    const int*   __restrict__ labels,          // [B,K]
    const unsigned short* __restrict__ tab,    // [chunk][256] packed fp16
    const float* __restrict__ base_ev,         // [D]
    const float* __restrict__ base_ar,         // [D]
    float* __restrict__ acc_num,               // [B,D] (chunked path)
    float* __restrict__ acc_den,               // [B,D]
    float* __restrict__ out,                   // [B,D] (fused path)
    int K, int c0, int c1, int fused) {
    __shared__ float w_s[128];
    __shared__ int   lab_s[128];
    __shared__ float rn[8][DD];
    __shared__ float rd[8][DD];

    int b = blockIdx.x;
    int tid = threadIdx.x;
    if (tid < K) {
        float sqd = sq_dists[(size_t)b * K + tid];
        w_s[tid]  = (sqd <= TAU2) ? __expf(-sqd) : 0.0f;
        lab_s[tid] = labels[(size_t)b * K + tid];
    }
    __syncthreads();

    int wid = tid >> 6;
    int lane = tid & 63;
    int j = lane & 31;
    int h = lane >> 5;
    const unsigned short* jbase = tab + (size_t)j * 8;

    float n0 = 0.f, n1 = 0.f, n2 = 0.f, n3 = 0.f;
    float d0 = 0.f, d1 = 0.f, d2 = 0.f, d3 = 0.f;

    if (fused && K == 128) {
        int k0 = wid << 5;
        uint4 p[8];
        float wk[8];
        #pragma unroll
        for (int i = 0; i < 8; ++i) {
            int k = k0 + 2 * i + h;
            wk[i] = w_s[k];
            p[i] = *(const uint4*)(jbase + (size_t)lab_s[k] * 256);
        }
        #pragma unroll
        for (int i = 0; i < 8; ++i) {
            float2 e01 = __half22float2(*(const __half2*)&p[i].x);
            float2 e23 = __half22float2(*(const __half2*)&p[i].y);
            float2 a01 = __half22float2(*(const __half2*)&p[i].z);
            float2 a23 = __half22float2(*(const __half2*)&p[i].w);
            float w = wk[i];
            n0 = fmaf(w, e01.x, n0); n1 = fmaf(w, e01.y, n1);
            n2 = fmaf(w, e23.x, n2); n3 = fmaf(w, e23.y, n3);
            d0 = fmaf(w, a01.x, d0); d1 = fmaf(w, a01.y, d1);
            d2 = fmaf(w, a23.x, d2); d3 = fmaf(w, a23.y, d3);
        }
        #pragma unroll
        for (int i = 0; i < 8; ++i) {
            int k = k0 + 16 + 2 * i + h;
            wk[i] = w_s[k];
            p[i] = *(const uint4*)(jbase + (size_t)lab_s[k] * 256);
        }
        #pragma unroll
        for (int i = 0; i < 8; ++i) {
            float2 e01 = __half22float2(*(const __half2*)&p[i].x);
            float2 e23 = __half22float2(*(const __half2*)&p[i].y);
            float2 a01 = __half22float2(*(const __half2*)&p[i].z);
            float2 a23 = __half22float2(*(const __half2*)&p[i].w);
            float w = wk[i];
            n0 = fmaf(w, e01.x, n0); n1 = fmaf(w, e01.y, n1);
            n2 = fmaf(w, e23.x, n2); n3 = fmaf(w, e23.y, n3);
            d0 = fmaf(w, a01.x, d0); d1 = fmaf(w, a01.y, d1);
            d2 = fmaf(w, a23.x, d2); d3 = fmaf(w, a23.y, d3);
        }
    } else {
        int kpw = (K + 3) >> 2;
        for (int kk = h; kk < kpw; kk += 2) {
            int k = wid * kpw + kk;
            if (k >= K) break;
            int l = lab_s[k];
            if (l >= c0 && l < c1) {
                float w = w_s[k];
                uint4 pkt = *(const uint4*)(jbase + (size_t)(l - c0) * 256);
                float2 e01 = __half22float2(*(const __half2*)&pkt.x);
                float2 e23 = __half22float2(*(const __half2*)&pkt.y);
                float2 a01 = __half22float2(*(const __half2*)&pkt.z);
                float2 a23 = __half22float2(*(const __half2*)&pkt.w);
                n0 = fmaf(w, e01.x, n0); n1 = fmaf(w, e01.y, n1);
                n2 = fmaf(w, e23.x, n2); n3 = fmaf(w, e23.y, n3);
                d0 = fmaf(w, a01.x, d0); d1 = fmaf(w, a01.y, d1);
                d2 = fmaf(w, a23.x, d2); d3 = fmaf(w, a23.y, d3);
            }
        }
    }
    int part = wid * 2 + h;
    *(float4*)&rn[part][4 * j] = make_float4(n0, n1, n2, n3);
    *(float4*)&rd[part][4 * j] = make_float4(d0, d1, d2, d3);
    __syncthreads();

    if (tid < DD) {
        float n  = rn[0][tid] + rn[1][tid] + rn[2][tid] + rn[3][tid]
                 + rn[4][tid] + rn[5][tid] + rn[6][tid] + rn[7][tid];
        float dn = rd[0][tid] + rd[1][tid] + rd[2][tid] + rd[3][tid]
                 + rd[4][tid] + rd[5][tid] + rd[6][tid] + rd[7][tid];
        size_t o = (size_t)b * DD + tid;
        if (fused) {
            n  += base_ev[tid];
            dn += base_ar[tid] + EPSV;
            float r = n / dn;
            out[o] = fminf(fmaxf(r, EPSV), 1.0f - EPSV);
        } else {
            acc_num[o] += n;
            acc_den[o] += dn;
        }
    }
}

// ---------------------------------------------------------------------------
// Finalize (chunked fallback only)
// ---------------------------------------------------------------------------
__global__ void finalize_kernel(const float* __restrict__ acc_num,
                                const float* __restrict__ acc_den,
                                const float* __restrict__ base_ev,
                                const float* __restrict__ base_ar,
                                float* __restrict__ out, int total) {
    int i = blockIdx.x * blockDim.x + threadIdx.x;
    if (i >= total) return;
    int d = i & (DD - 1);
    float n  = acc_num[i] + base_ev[d];
    float dn = acc_den[i] + base_ar[d] + EPSV;
    float r = n / dn;
    r = fminf(fmaxf(r, EPSV), 1.0f - EPSV);
    out[i] = r;
}

extern "C" void kernel_launch(void* const* d_in, const int* in_sizes, int n_in,
                              void* d_out, int out_size, void* d_ws, size_t ws_size,
                              hipStream_t stream) {
    const float* sq_dists = (const float*)d_in[0];
    const float* log_ev   = (const float*)d_in[1];
    const float* log_cen  = (const float*)d_in[2];
    const float* log_be   = (const float*)d_in[3];
    const float* log_bc   = (const float*)d_in[4];
    const int*   labels   = (const int*)d_in[5];
    float* out = (float*)d_out;

    const int Dv = in_sizes[3];                        // 128
    const long long E = (long long)in_sizes[1] / Dv;   // 100000
    const int B = out_size / Dv;                       // 4096
    const int K = in_sizes[0] / B;                     // 128

    // ws layout: [acc_num B*D][acc_den B*D][base_ev D][base_ar D][table ...]
    float* ws = (float*)d_ws;
    float* acc_num = ws;
    float* acc_den = acc_num + (size_t)B * Dv;
    float* base_ev = acc_den + (size_t)B * Dv;
    float* base_ar = base_ev + Dv;
    size_t head_floats = 2 * (size_t)B * Dv + 2 * (size_t)Dv;
    unsigned short* tab = (unsigned short*)(ws + head_floats);

    size_t head_bytes = head_floats * sizeof(float);
    long long cap = 0;
    if (ws_size > head_bytes)
        cap = (long long)((ws_size - head_bytes) / (2 * (size_t)Dv * sizeof(unsigned short)));
    long long chunk = cap > E ? E : cap;
    if (chunk < 1) chunk = 1;

    if (chunk >= E) {
        prep_kernel<<<4096, 256, 0, stream>>>(log_ev, log_cen, log_be, log_bc,
                                              tab, base_ev, base_ar, 0, E, 1);
        gather_kernel<<<B, 256, 0, stream>>>(sq_dists, labels, tab,
                                             base_ev, base_ar,
                                             acc_num, acc_den, out,
                                             K, 0, (int)E, 1);
    } else {
        hipMemsetAsync(acc_num, 0, 2 * (size_t)B * Dv * sizeof(float), stream);
        for (long long c0 = 0; c0 < E; c0 += chunk) {
            long long c1 = c0 + chunk; if (c1 > E) c1 = E;
            long long rows = c1 - c0;
            prep_kernel<<<4096, 256, 0, stream>>>(log_ev, log_cen, log_be, log_bc,
                                                  tab, base_ev, base_ar,
                                                  c0, rows, c0 == 0 ? 1 : 0);
            gather_kernel<<<B, 256, 0, stream>>>(sq_dists, labels, tab,
                                                 base_ev, base_ar,
                                                 acc_num, acc_den, out,
                                                 K, (int)c0, (int)c1, 0);
        }
        finalize_kernel<<<(B * Dv + 255) / 256, 256, 0, stream>>>(
            acc_num, acc_den, base_ev, base_ar, out, B * Dv);
    }
}